// Round 1
// baseline (181.869 us; speedup 1.0000x reference)
//
#include <hip/hip_runtime.h>
#include <math.h>

// Problem constants (fixed by reference setup_inputs)
#define B_ROWS 8192
#define DIM    128
#define KNEG   256
#define INV_T  (1.0f / 0.07f)

// ---------------- Pass 1: reciprocal norms of each row of z1 and z2 ----------
// One wave (64 lanes) per row; each lane loads float2 (coalesced 512B/row).
__global__ __launch_bounds__(256)
void rnorm_kernel(const float* __restrict__ z1, const float* __restrict__ z2,
                  float* __restrict__ rn1, float* __restrict__ rn2) {
    int wave = blockIdx.x * (blockDim.x >> 6) + (threadIdx.x >> 6);
    int lane = threadIdx.x & 63;
    const float* src;
    float* dst;
    int row;
    if (wave < B_ROWS) { src = z1; dst = rn1; row = wave; }
    else               { src = z2; dst = rn2; row = wave - B_ROWS; }
    const float2* p = reinterpret_cast<const float2*>(src + (size_t)row * DIM);
    float2 v = p[lane];
    float ss = v.x * v.x + v.y * v.y;
    #pragma unroll
    for (int o = 32; o > 0; o >>= 1) ss += __shfl_xor(ss, o, 64);
    if (lane == 0) {
        float n = sqrtf(ss);
        dst[row] = 1.0f / fmaxf(n, 1e-12f);
    }
}

// ---------------- Pass 2: per-row InfoNCE loss --------------------------------
// One block (256 threads) per row b. Thread t owns negative k=t.
// dot(z1n[b], z2n[j]) = rawdot * rn1[b] * rn2[j]; z1 row pre-scaled in LDS.
__global__ __launch_bounds__(256)
void infonce_main(const float* __restrict__ z1, const float* __restrict__ z2,
                  const int* __restrict__ idx,
                  const float* __restrict__ rn1, const float* __restrict__ rn2,
                  float* __restrict__ partial) {
    int b = blockIdx.x;
    int t = threadIdx.x;
    int wid = t >> 6, lane = t & 63;

    __shared__ float s_z1[DIM];
    __shared__ float s_red[8];
    __shared__ float s_scalar[2];

    float rn1b = rn1[b];
    if (t < DIM) s_z1[t] = z1[(size_t)b * DIM + t] * rn1b;
    __syncthreads();

    // positive similarity: dot(s_z1, z2[b]) * rn2[b] / T
    float pp = 0.f;
    if (t < DIM) pp = s_z1[t] * z2[(size_t)b * DIM + t];
    #pragma unroll
    for (int o = 32; o > 0; o >>= 1) pp += __shfl_xor(pp, o, 64);
    if (lane == 0) s_red[wid] = pp;
    __syncthreads();
    if (t == 0) s_scalar[0] = (s_red[0] + s_red[1]) * rn2[b] * INV_T;
    __syncthreads();
    float pos = s_scalar[0];

    // negative similarity for k = t
    int j = idx[(size_t)b * KNEG + t];
    const float4* vrow = reinterpret_cast<const float4*>(z2 + (size_t)j * DIM);
    const float4* a4   = reinterpret_cast<const float4*>(s_z1);
    float acc = 0.f;
    #pragma unroll
    for (int d = 0; d < DIM / 4; ++d) {
        float4 a = a4[d];      // LDS broadcast (all lanes same addr)
        float4 v = vrow[d];    // gather from L2/L3-resident z2
        acc += a.x * v.x + a.y * v.y + a.z * v.z + a.w * v.w;
    }
    float logit = acc * rn2[j] * INV_T;

    // block max over 256 logits + pos
    float m = logit;
    #pragma unroll
    for (int o = 32; o > 0; o >>= 1) m = fmaxf(m, __shfl_xor(m, o, 64));
    if (lane == 0) s_red[wid] = m;
    __syncthreads();
    if (t == 0) {
        float mm = fmaxf(fmaxf(s_red[0], s_red[1]), fmaxf(s_red[2], s_red[3]));
        s_scalar[1] = fmaxf(mm, pos);
    }
    __syncthreads();
    m = s_scalar[1];

    // sum of exp
    float e = expf(logit - m);
    #pragma unroll
    for (int o = 32; o > 0; o >>= 1) e += __shfl_xor(e, o, 64);
    if (lane == 0) s_red[4 + wid] = e;
    __syncthreads();
    if (t == 0) {
        float s = s_red[4] + s_red[5] + s_red[6] + s_red[7] + expf(pos - m);
        partial[b] = m + logf(s) - pos;   // lse - pos
    }
}

// ---------------- Pass 3: deterministic mean over 8192 partials --------------
__global__ __launch_bounds__(256)
void reduce_kernel(const float* __restrict__ partial, float* __restrict__ out) {
    int t = threadIdx.x;
    float s = 0.f;
    for (int i = t; i < B_ROWS; i += 256) s += partial[i];
    #pragma unroll
    for (int o = 32; o > 0; o >>= 1) s += __shfl_xor(s, o, 64);
    __shared__ float sr[4];
    if ((t & 63) == 0) sr[t >> 6] = s;
    __syncthreads();
    if (t == 0) out[0] = (sr[0] + sr[1] + sr[2] + sr[3]) / (float)B_ROWS;
}

extern "C" void kernel_launch(void* const* d_in, const int* in_sizes, int n_in,
                              void* d_out, int out_size, void* d_ws, size_t ws_size,
                              hipStream_t stream) {
    const float* z1 = (const float*)d_in[0];
    const float* z2 = (const float*)d_in[1];
    const int* idx  = (const int*)d_in[2];   // jax default x64-disabled -> int32
    float* out = (float*)d_out;

    float* rn1     = (float*)d_ws;                 // [B]
    float* rn2     = rn1 + B_ROWS;                 // [B]
    float* partial = rn2 + B_ROWS;                 // [B]

    // pass 1: 2*B rows, 4 waves/block
    rnorm_kernel<<<(2 * B_ROWS) / 4, 256, 0, stream>>>(z1, z2, rn1, rn2);
    // pass 2: one block per row
    infonce_main<<<B_ROWS, 256, 0, stream>>>(z1, z2, idx, rn1, rn2, partial);
    // pass 3: single block, deterministic
    reduce_kernel<<<1, 256, 0, stream>>>(partial, out);
}

// Round 2
// 89.703 us; speedup vs baseline: 2.0275x; 2.0275x over previous
//
#include <hip/hip_runtime.h>
#include <math.h>

// Problem constants (fixed by reference setup_inputs)
#define B_ROWS 8192
#define DIM    128
#define KNEG   256
#define INV_T  (1.0f / 0.07f)

// ---------------- Pass 1: reciprocal norms of each row of z1 and z2 ----------
// One wave (64 lanes) per row; lane loads float2 (coalesced 512B/row).
__global__ __launch_bounds__(256)
void rnorm_kernel(const float* __restrict__ z1, const float* __restrict__ z2,
                  float* __restrict__ rn1, float* __restrict__ rn2) {
    int wave = blockIdx.x * 4 + (threadIdx.x >> 6);
    int lane = threadIdx.x & 63;
    const float* src; float* dst; int row;
    if (wave < B_ROWS) { src = z1; dst = rn1; row = wave; }
    else               { src = z2; dst = rn2; row = wave - B_ROWS; }
    const float2* p = reinterpret_cast<const float2*>(src + (size_t)row * DIM);
    float2 v = p[lane];
    float ss = v.x * v.x + v.y * v.y;
    #pragma unroll
    for (int o = 32; o > 0; o >>= 1) ss += __shfl_xor(ss, o, 64);
    if (lane == 0) dst[row] = 1.0f / fmaxf(sqrtf(ss), 1e-12f);
}

// ---------------- Pass 2: per-row InfoNCE loss --------------------------------
// One block (256 threads) per row b. COALESCED gather: each 16-lane group
// cooperatively reads one negative row (2x float4/lane = 512B contiguous),
// dots against register-held pre-scaled z1 fragments, reduces over 16 lanes.
// Iteration i (0..15) handles negatives {w*64 + 4i + g}; lane q==i keeps the
// logit, so each of the 256 threads ends holding exactly one distinct logit.
__global__ __launch_bounds__(256)
void infonce_main(const float* __restrict__ z1, const float* __restrict__ z2,
                  const int* __restrict__ idx,
                  const float* __restrict__ rn1, const float* __restrict__ rn2,
                  float* __restrict__ partial) {
    int b = blockIdx.x;
    int t = threadIdx.x;
    int wid = t >> 6, lane = t & 63;
    int g = lane >> 4;       // group 0..3 within wave
    int q = lane & 15;       // position within group

    // z1 fragments for this lane's q (same across waves/groups), pre-scaled
    float rn1b = rn1[b];
    const float4* z1r = reinterpret_cast<const float4*>(z1 + (size_t)b * DIM);
    float4 a0 = z1r[q];
    float4 a1 = z1r[16 + q];
    a0.x *= rn1b; a0.y *= rn1b; a0.z *= rn1b; a0.w *= rn1b;
    a1.x *= rn1b; a1.y *= rn1b; a1.z *= rn1b; a1.w *= rn1b;

    // positive similarity (computed redundantly by every wave; identical)
    const float4* pz = reinterpret_cast<const float4*>(z2 + (size_t)b * DIM);
    float4 p0 = pz[q], p1 = pz[16 + q];
    float pp = a0.x * p0.x + a0.y * p0.y + a0.z * p0.z + a0.w * p0.w
             + a1.x * p1.x + a1.y * p1.y + a1.z * p1.z + a1.w * p1.w;
    #pragma unroll
    for (int o = 1; o < 16; o <<= 1) pp += __shfl_xor(pp, o, 64);
    float pos = pp * rn2[b] * INV_T;

    // 64 negatives per wave, 4 per iteration (one per 16-lane group)
    const int* idx_row = idx + (size_t)b * KNEG + wid * 64;
    float mylogit = -1e30f;
    #pragma unroll
    for (int i = 0; i < 16; ++i) {
        int j = idx_row[i * 4 + g];
        const float4* r = reinterpret_cast<const float4*>(z2 + (size_t)j * DIM);
        float4 v0 = r[q];
        float4 v1 = r[16 + q];
        float pd = a0.x * v0.x + a0.y * v0.y + a0.z * v0.z + a0.w * v0.w
                 + a1.x * v1.x + a1.y * v1.y + a1.z * v1.z + a1.w * v1.w;
        #pragma unroll
        for (int o = 1; o < 16; o <<= 1) pd += __shfl_xor(pd, o, 64);
        float logit = pd * rn2[j] * INV_T;
        if (q == i) mylogit = logit;
    }

    // block max over the 256 logits, then include pos
    __shared__ float s_red[8];
    float m = mylogit;
    #pragma unroll
    for (int o = 1; o < 64; o <<= 1) m = fmaxf(m, __shfl_xor(m, o, 64));
    if (lane == 0) s_red[wid] = m;
    __syncthreads();
    float mm = fmaxf(fmaxf(s_red[0], s_red[1]), fmaxf(s_red[2], s_red[3]));
    mm = fmaxf(mm, pos);

    // sum of exp
    float e = expf(mylogit - mm);
    #pragma unroll
    for (int o = 1; o < 64; o <<= 1) e += __shfl_xor(e, o, 64);
    if (lane == 0) s_red[4 + wid] = e;
    __syncthreads();
    if (t == 0) {
        float s = s_red[4] + s_red[5] + s_red[6] + s_red[7] + expf(pos - mm);
        partial[b] = mm + logf(s) - pos;   // lse - pos
    }
}

// ---------------- Pass 3: deterministic mean over 8192 partials --------------
__global__ __launch_bounds__(256)
void reduce_kernel(const float* __restrict__ partial, float* __restrict__ out) {
    int t = threadIdx.x;
    float s = 0.f;
    for (int i = t; i < B_ROWS; i += 256) s += partial[i];
    #pragma unroll
    for (int o = 32; o > 0; o >>= 1) s += __shfl_xor(s, o, 64);
    __shared__ float sr[4];
    if ((t & 63) == 0) sr[t >> 6] = s;
    __syncthreads();
    if (t == 0) out[0] = (sr[0] + sr[1] + sr[2] + sr[3]) / (float)B_ROWS;
}

extern "C" void kernel_launch(void* const* d_in, const int* in_sizes, int n_in,
                              void* d_out, int out_size, void* d_ws, size_t ws_size,
                              hipStream_t stream) {
    const float* z1 = (const float*)d_in[0];
    const float* z2 = (const float*)d_in[1];
    const int* idx  = (const int*)d_in[2];
    float* out = (float*)d_out;

    float* rn1     = (float*)d_ws;       // [B]
    float* rn2     = rn1 + B_ROWS;       // [B]
    float* partial = rn2 + B_ROWS;       // [B]

    rnorm_kernel<<<(2 * B_ROWS) / 4, 256, 0, stream>>>(z1, z2, rn1, rn2);
    infonce_main<<<B_ROWS, 256, 0, stream>>>(z1, z2, idx, rn1, rn2, partial);
    reduce_kernel<<<1, 256, 0, stream>>>(partial, out);
}